// Round 9
// baseline (224.389 us; speedup 1.0000x reference)
//
#include <hip/hip_runtime.h>
#include <hip/hip_bf16.h>

#define BN 8
#define LN 4096
#define HN 2048
#define EN 512
#define KN 64
#define LT 32
#define NIT 128

typedef __attribute__((ext_vector_type(8))) short bf16x8;
typedef __attribute__((ext_vector_type(4))) float f32x4;
typedef __attribute__((ext_vector_type(16))) float f32x16;
typedef __attribute__((ext_vector_type(4))) unsigned u32x4;

__device__ __forceinline__ short f2b(float x) {
  union { float f; unsigned u; } v; v.f = x;
  unsigned r = v.u + 0x7fffu + ((v.u >> 16) & 1u);  // RNE f32->bf16
  return (short)(r >> 16);
}

__device__ __forceinline__ bf16x8 cvt8s(const float* __restrict__ p, float s) {
  f32x4 a = *(const f32x4*)(p);
  f32x4 b = *(const f32x4*)(p + 4);
  bf16x8 r;
  r[0] = f2b(a[0] * s); r[1] = f2b(a[1] * s); r[2] = f2b(a[2] * s); r[3] = f2b(a[3] * s);
  r[4] = f2b(b[0] * s); r[5] = f2b(b[1] * s); r[6] = f2b(b[2] * s); r[7] = f2b(b[3] * s);
  return r;
}

__device__ __forceinline__ void gload16(const void* g, void* s) {
  __builtin_amdgcn_global_load_lds(
      (const __attribute__((address_space(1))) unsigned int*)(unsigned long long)g,
      (__attribute__((address_space(3))) unsigned int*)(unsigned int)(unsigned long long)s,
      16, 0, 0);
}

// ---------- prep1: cvt x/y (blocks 0..1535) | stats (1536..2559) ----------
__global__ __launch_bounds__(256) void k_prep1(const float* __restrict__ xd,
                                               short* __restrict__ xo,
                                               const float* __restrict__ yd,
                                               short* __restrict__ yo,
                                               float* __restrict__ ps) {
  const int bx = blockIdx.x;
  const int tid = threadIdx.x;
  const float c0 = 0.125f * 1.4426950408889634f;  // scale * log2(e)
  if (bx < 1536) {
    const float* src;
    short* dst;
    float scale;
    int i;
    if (bx < 1024) { i = bx * 256 + tid; src = xd; dst = xo; scale = c0; }
    else           { i = (bx - 1024) * 256 + tid; src = yd; dst = yo; scale = 1.0f; }
    *(bf16x8*)(dst + (size_t)i * 8) = cvt8s(src + (size_t)i * 8, scale);
  } else {
    // stats: ps[hc][b][l] = sum over 512 h of 2^u  (same rounding as cvt path)
    const int idx = bx - 1536;
    const int b = (idx >> 5) & 7, hc = idx >> 8;
    const int w = tid >> 6, lane = tid & 63;
    const int row = lane & 15, g = lane >> 4;
    const int lb = (idx & 31) * 128 + w * 32;
    const size_t bL = (size_t)b * LN, bH = (size_t)b * HN;
    bf16x8 xa[2][2];
#pragma unroll
    for (int lt = 0; lt < 2; ++lt) {
      const float* xp = xd + (bL + lb + lt * 16 + row) * KN + g * 8;
      xa[lt][0] = cvt8s(xp, c0);
      xa[lt][1] = cvt8s(xp + 32, c0);
    }
    float s[2][4] = {{0.f, 0.f, 0.f, 0.f}, {0.f, 0.f, 0.f, 0.f}};
    const float* ybase = yd + (bH + hc * 512 + row) * KN + g * 8;
#pragma unroll 2
    for (int it = 0; it < 32; ++it) {
      const float* yp = ybase + (size_t)it * (16 * KN);
      bf16x8 y0 = cvt8s(yp, 1.0f);
      bf16x8 y1 = cvt8s(yp + 32, 1.0f);
#pragma unroll
      for (int lt = 0; lt < 2; ++lt) {
        f32x4 a = {0.f, 0.f, 0.f, 0.f};
        a = __builtin_amdgcn_mfma_f32_16x16x32_bf16(xa[lt][0], y0, a, 0, 0, 0);
        a = __builtin_amdgcn_mfma_f32_16x16x32_bf16(xa[lt][1], y1, a, 0, 0, 0);
#pragma unroll
        for (int r = 0; r < 4; ++r) s[lt][r] += __builtin_amdgcn_exp2f(a[r]);
      }
    }
#pragma unroll
    for (int d = 1; d < 16; d <<= 1)
#pragma unroll
      for (int lt = 0; lt < 2; ++lt)
#pragma unroll
        for (int r = 0; r < 4; ++r) s[lt][r] += __shfl_xor(s[lt][r], d);
    if (row == 0) {
#pragma unroll
      for (int lt = 0; lt < 2; ++lt)
#pragma unroll
        for (int r = 0; r < 4; ++r)
          ps[(size_t)hc * (BN * LN) + bL + lb + lt * 16 + 4 * g + r] = s[lt][r];
    }
  }
}

__global__ void k_comb(const float* __restrict__ ps, float* __restrict__ wv) {
  int idx = blockIdx.x * 256 + threadIdx.x;
  float z = ps[idx] + ps[BN * LN + idx] + ps[2 * BN * LN + idx] + ps[3 * BN * LN + idx];
  wv[idx] = 1.0f / z;
}

// ---------- prep2: vals [b][l][e] f32 * wv[b][l] -> valsT [b][e][l] bf16 ----------
__global__ __launch_bounds__(256) void k_prep2(const float* __restrict__ vals,
                                               const float* __restrict__ wv,
                                               short* __restrict__ valsT) {
  __shared__ unsigned trT[2048];
  const int idx = blockIdx.x;
  const int tid = threadIdx.x;
  const int b = idx >> 9;
  const int e0 = ((idx >> 6) & 7) * 64;
  const int l0 = (idx & 63) * 64;
  {
    int lr2 = tid >> 3;
    int ec = (tid & 7) * 8;
    const float* r0 = vals + ((size_t)b * LN + l0 + 2 * lr2) * EN + e0 + ec;
    const float* r1 = r0 + EN;
    float w0 = wv[(size_t)b * LN + l0 + 2 * lr2];
    float w1 = wv[(size_t)b * LN + l0 + 2 * lr2 + 1];
    f32x4 a0 = *(const f32x4*)r0, a1 = *(const f32x4*)(r0 + 4);
    f32x4 cc0 = *(const f32x4*)r1, cc1 = *(const f32x4*)(r1 + 4);
#pragma unroll
    for (int j = 0; j < 8; ++j) {
      float lo = ((j < 4) ? a0[j] : a1[j - 4]) * w0;
      float hi = ((j < 4) ? cc0[j] : cc1[j - 4]) * w1;
      unsigned dw = (unsigned)(unsigned short)f2b(lo) |
                    ((unsigned)(unsigned short)f2b(hi) << 16);
      int e = ec + j;
      int sz = (((e >> 3) ^ e) & 7) << 2;
      trT[e * 32 + (lr2 ^ sz)] = dw;
    }
  }
  __syncthreads();
  {
    int er = tid >> 2, lq = (tid & 3) * 8;
    int sr = ((er >> 3) ^ er) & 7;
    const unsigned* base = trT + er * 32;
    u32x4 u0 = *(const u32x4*)(base + ((((lq >> 2) + 0) ^ sr) << 2));
    u32x4 u1 = *(const u32x4*)(base + ((((lq >> 2) + 1) ^ sr) << 2));
    short* dst = valsT + ((size_t)b * EN + e0 + er) * LN + l0 + 2 * lq;
    *(u32x4*)dst = u0;
    *(u32x4*)(dst + 8) = u1;
  }
}

// ---------- main v8: in-register P (swapped 32x32 produce + permlane32_swap) ----------
// 4 waves, wave tile 32h x 128e, LT=32, 1 barrier/iter.
// LDS: vT[3]x16384 @0 | xT[3]x4096 @49152   (61440 B, no pT, no sw)
__global__ __launch_bounds__(256, 2) void k_main8(
    const short* __restrict__ valsT, const short* __restrict__ xb,
    const short* __restrict__ yb, float* __restrict__ out) {
  __shared__ __align__(16) char smem[61440];
  const int tid = threadIdx.x;
  const int w = tid >> 6, lane = tid & 63;
  const int l5 = lane & 31, hi = lane >> 5;

  const int f = blockIdx.x;
  const int b = f & 7;                 // XCD f%8 <- batch b (valsT[b] 4MB per XCD L2)
  const int rest = f >> 3;             // 0..63
  const int hb = (rest & 31) * 64;
  const int eb = (rest >> 5) * 256;
  const size_t bL = (size_t)b * LN, bH = (size_t)b * HN;
  const int hh = w >> 1, eq = w & 1;

  // ---- staging source pointers (pre-swizzled global, linear LDS dest) ----
  const short* vsrc[4];
#pragma unroll
  for (int j = 0; j < 4; ++j) {
    int i = j * 256 + tid;
    int e = i >> 2, c = i & 3, sl = c ^ (e & 3);
    vsrc[j] = valsT + (((size_t)b * EN + eb + e) << 12) + 8 * sl;
  }
  const short* xsrc = xb + ((bL + (tid >> 3)) << 6) + 8 * ((tid & 7) ^ ((tid >> 3) & 7));

  auto stage = [&](int t) {
    int m3 = t % 3;
    gload16(xsrc + ((size_t)t << 11), smem + 49152 + m3 * 4096 + tid * 16);
#pragma unroll
    for (int j = 0; j < 4; ++j)
      gload16(vsrc[j] + t * 32, smem + m3 * 16384 + (j * 256 + tid) * 16);
  };

  // ---- y B-frags (loop-invariant): y[h = hb+hh*32+l5][k=16kf+8hi+j] ----
  bf16x8 ya[4];
  {
    const short* yp = yb + ((bH + hb + hh * 32 + l5) << 6) + hi * 8;
#pragma unroll
    for (int kf = 0; kf < 4; ++kf) ya[kf] = *(const bf16x8*)(yp + kf * 16);
  }
  // xT read offsets: row l5 (128B), chunk (2kf+hi)^(l5&7)
  int xoff[4];
#pragma unroll
  for (int kf = 0; kf < 4; ++kf)
    xoff[kf] = l5 * 128 + (((2 * kf + hi) ^ (l5 & 7)) << 4);
  // vT read offsets: row e (64B), chunk (2kh+hi)^(e&3)
  int voff[4][2];
#pragma unroll
  for (int et = 0; et < 4; ++et) {
    int e = eq * 128 + et * 32 + l5;
#pragma unroll
    for (int kh = 0; kh < 2; ++kh)
      voff[et][kh] = e * 64 + (((2 * kh + hi) ^ (e & 3)) << 4);
  }

  f32x16 acc[4];
#pragma unroll
  for (int et = 0; et < 4; ++et)
#pragma unroll
    for (int q = 0; q < 16; ++q) acc[et][q] = 0.f;

  // ---- prologue: stage 0,1; drain tile0's 5, leave tile1's 5 in flight ----
  stage(0);
  stage(1);
  asm volatile("s_waitcnt vmcnt(5)" ::: "memory");
  __builtin_amdgcn_s_barrier();
  asm volatile("" ::: "memory");

  for (int it = 0; it < NIT; ++it) {
    const char* vbuf = smem + (it % 3) * 16384;
    const char* xbuf = smem + 49152 + (it % 3) * 4096;
    if (it + 2 < NIT) stage(it + 2);

    // V fragments (this tile, independent of produce)
    bf16x8 vb[4][2];
#pragma unroll
    for (int et = 0; et < 4; ++et) {
      vb[et][0] = *(const bf16x8*)(vbuf + voff[et][0]);
      vb[et][1] = *(const bf16x8*)(vbuf + voff[et][1]);
    }

    // produce S^T: D[row=l][col=h] = x * y  (32x32, K=64)
    f32x16 d;
#pragma unroll
    for (int q = 0; q < 16; ++q) d[q] = 0.f;
#pragma unroll
    for (int kf = 0; kf < 4; ++kf) {
      bf16x8 xa = *(const bf16x8*)(xbuf + xoff[kf]);
      d = __builtin_amdgcn_mfma_f32_32x32x16_bf16(xa, ya[kf], d, 0, 0, 0);
    }

    // P = exp2(S) -> bf16 pairs -> permlane32_swap into A-frag layout
    int dw[8];
#pragma unroll
    for (int q = 0; q < 8; ++q) {
      float plo = __builtin_amdgcn_exp2f(d[2 * q]);
      float phi = __builtin_amdgcn_exp2f(d[2 * q + 1]);
      asm("v_cvt_pk_bf16_f32 %0, %1, %2" : "=v"(dw[q]) : "v"(plo), "v"(phi));
    }
    asm volatile("v_permlane32_swap_b32 %0, %1" : "+v"(dw[0]), "+v"(dw[2]));
    asm volatile("v_permlane32_swap_b32 %0, %1" : "+v"(dw[1]), "+v"(dw[3]));
    asm volatile("v_permlane32_swap_b32 %0, %1" : "+v"(dw[4]), "+v"(dw[6]));
    asm volatile("v_permlane32_swap_b32 %0, %1" : "+v"(dw[5]), "+v"(dw[7]));
    union { int i[4]; bf16x8 v; } pa0, pa1;
    pa0.i[0] = dw[0]; pa0.i[1] = dw[1]; pa0.i[2] = dw[2]; pa0.i[3] = dw[3];
    pa1.i[0] = dw[4]; pa1.i[1] = dw[5]; pa1.i[2] = dw[6]; pa1.i[3] = dw[7];

    // consume: acc[h][e] += P x V'   (32x32, K=32 per tile)
    __builtin_amdgcn_s_setprio(1);
#pragma unroll
    for (int et = 0; et < 4; ++et) {
      acc[et] = __builtin_amdgcn_mfma_f32_32x32x16_bf16(pa0.v, vb[et][0], acc[et], 0, 0, 0);
      acc[et] = __builtin_amdgcn_mfma_f32_32x32x16_bf16(pa1.v, vb[et][1], acc[et], 0, 0, 0);
    }
    __builtin_amdgcn_s_setprio(0);

    if (it < NIT - 1) {
      if (it < NIT - 2)
        asm volatile("s_waitcnt vmcnt(5) lgkmcnt(0)" ::: "memory");
      else
        asm volatile("s_waitcnt vmcnt(0) lgkmcnt(0)" ::: "memory");
      __builtin_amdgcn_s_barrier();
      asm volatile("" ::: "memory");
    }
  }

  // ---- epilogue: D layout col=lane&31 (e), row=(r&3)+8*(r>>2)+4*hi (h) ----
#pragma unroll
  for (int et = 0; et < 4; ++et)
#pragma unroll
    for (int r = 0; r < 16; ++r) {
      int h = hb + hh * 32 + (r & 3) + 8 * (r >> 2) + 4 * hi;
      int e = eb + eq * 128 + et * 32 + l5;
      out[(bH + h) * (size_t)EN + e] = acc[et][r];
    }
}

// ================= fallback path (round-1 kernels, ws < 40.5 MB) =================
__global__ __launch_bounds__(256) void k_stats_o(const float* __restrict__ xd,
                                                 const float* __restrict__ yd,
                                                 float* __restrict__ mz) {
  const int b = blockIdx.y;
  const int w = threadIdx.x >> 6;
  const int lane = threadIdx.x & 63;
  const int row = lane & 15, g = lane >> 4;
  const int lb = blockIdx.x * 64 + w * 16;
  const float* xp = xd + ((size_t)b * LN + lb + row) * KN + g * 8;
  bf16x8 a0 = cvt8s(xp, 1.0f), a1 = cvt8s(xp + 32, 1.0f);
  float m[4], s[4];
#pragma unroll
  for (int r = 0; r < 4; ++r) { m[r] = -1e30f; s[r] = 0.f; }
  const float* ybp = yd + ((size_t)b * HN + row) * KN + g * 8;
  for (int h0 = 0; h0 < HN; h0 += 16) {
    bf16x8 b0 = cvt8s(ybp + (size_t)h0 * KN, 1.0f);
    bf16x8 b1 = cvt8s(ybp + (size_t)h0 * KN + 32, 1.0f);
    f32x4 acc = {0.f, 0.f, 0.f, 0.f};
    acc = __builtin_amdgcn_mfma_f32_16x16x32_bf16(a0, b0, acc, 0, 0, 0);
    acc = __builtin_amdgcn_mfma_f32_16x16x32_bf16(a1, b1, acc, 0, 0, 0);
#pragma unroll
    for (int r = 0; r < 4; ++r) {
      float v = acc[r] * 0.125f;
      float mn = fmaxf(m[r], v);
      s[r] = s[r] * __expf(m[r] - mn) + __expf(v - mn);
      m[r] = mn;
    }
  }
#pragma unroll
  for (int d = 1; d < 16; d <<= 1) {
#pragma unroll
    for (int r = 0; r < 4; ++r) {
      float mo = __shfl_xor(m[r], d);
      float so = __shfl_xor(s[r], d);
      float mn = fmaxf(m[r], mo);
      s[r] = s[r] * __expf(m[r] - mn) + so * __expf(mo - mn);
      m[r] = mn;
    }
  }
  if (row == 0) {
#pragma unroll
    for (int r = 0; r < 4; ++r) {
      size_t idx = (size_t)b * LN + lb + 4 * g + r;
      mz[idx] = m[r];
      mz[(size_t)BN * LN + idx] = 1.0f / s[r];
    }
  }
}

__global__ __launch_bounds__(512) void k_main_o(const float* __restrict__ vals,
                                                const float* __restrict__ xd,
                                                const float* __restrict__ yd,
                                                const float* __restrict__ mz,
                                                float* __restrict__ out) {
  __shared__ short vT[256][34];
  __shared__ short pT[128][34];
  __shared__ short xT[32][72];
  __shared__ float smm[32], smz[32];
  const int b = blockIdx.z;
  const int hb = blockIdx.x * 128;
  const int eb = blockIdx.y * 256;
  const int tid = threadIdx.x;
  const int w = tid >> 6, lane = tid & 63;
  const int row = lane & 15, g = lane >> 4;
  const float* yp = yd + ((size_t)b * HN + hb + w * 16 + row) * KN + g * 8;
  bf16x8 ya0 = cvt8s(yp, 1.0f), ya1 = cvt8s(yp + 32, 1.0f);
  f32x4 acc[16];
#pragma unroll
  for (int n = 0; n < 16; ++n) acc[n] = (f32x4){0.f, 0.f, 0.f, 0.f};
  const float* mzb = mz + (size_t)b * LN;
  const float* rzb = mz + (size_t)BN * LN + (size_t)b * LN;
  for (int l0 = 0; l0 < LN; l0 += 32) {
    __syncthreads();
    {
      int xl = tid >> 4, xk = (tid & 15) * 4;
      f32x4 xv = *(const f32x4*)(xd + ((size_t)b * LN + l0 + xl) * KN + xk);
      union { short h[4]; int i[2]; } u;
      u.h[0] = f2b(xv[0]); u.h[1] = f2b(xv[1]); u.h[2] = f2b(xv[2]); u.h[3] = f2b(xv[3]);
      int* dst = (int*)(&xT[xl][xk]);
      dst[0] = u.i[0]; dst[1] = u.i[1];
    }
#pragma unroll
    for (int lp = 0; lp < 4; ++lp) {
      int vl = (tid >> 6) + lp * 8;
      const float* vrow = vals + ((size_t)b * LN + l0 + vl) * EN + eb;
#pragma unroll
      for (int u2 = 0; u2 < 4; ++u2) {
        int e = (tid & 63) + u2 * 64;
        vT[e][vl] = f2b(vrow[e]);
      }
    }
    if (tid < 32) { smm[tid] = mzb[l0 + tid]; smz[tid] = rzb[l0 + tid]; }
    __syncthreads();
#pragma unroll
    for (int t2 = 0; t2 < 2; ++t2) {
      const short* xr = &xT[t2 * 16 + row][0];
      bf16x8 xb0 = *(const bf16x8*)(xr + 8 * g);
      bf16x8 xb1 = *(const bf16x8*)(xr + 32 + 8 * g);
      f32x4 sa = {0.f, 0.f, 0.f, 0.f};
      sa = __builtin_amdgcn_mfma_f32_16x16x32_bf16(ya0, xb0, sa, 0, 0, 0);
      sa = __builtin_amdgcn_mfma_f32_16x16x32_bf16(ya1, xb1, sa, 0, 0, 0);
      int lcol = t2 * 16 + row;
      float mm = smm[lcol], zz = smz[lcol];
#pragma unroll
      for (int r = 0; r < 4; ++r) {
        float p2 = __expf(sa[r] * 0.125f - mm) * zz;
        pT[w * 16 + 4 * g + r][lcol] = f2b(p2);
      }
    }
    __syncthreads();
    bf16x8 pa;
    {
      const int* pi = (const int*)(&pT[w * 16 + row][0] + 8 * g);
      union { int i[4]; bf16x8 f; } u;
      u.i[0] = pi[0]; u.i[1] = pi[1]; u.i[2] = pi[2]; u.i[3] = pi[3];
      pa = u.f;
    }
#pragma unroll
    for (int n = 0; n < 16; ++n) {
      const int* vi = (const int*)(&vT[n * 16 + row][0] + 8 * g);
      union { int i[4]; bf16x8 f; } u;
      u.i[0] = vi[0]; u.i[1] = vi[1]; u.i[2] = vi[2]; u.i[3] = vi[3];
      acc[n] = __builtin_amdgcn_mfma_f32_16x16x32_bf16(pa, u.f, acc[n], 0, 0, 0);
    }
  }
#pragma unroll
  for (int n = 0; n < 16; ++n)
#pragma unroll
    for (int r = 0; r < 4; ++r) {
      int h = hb + w * 16 + 4 * g + r;
      int e = eb + n * 16 + row;
      out[((size_t)b * HN + h) * EN + e] = acc[n][r];
    }
}

extern "C" void kernel_launch(void* const* d_in, const int* in_sizes, int n_in,
                              void* d_out, int out_size, void* d_ws, size_t ws_size,
                              hipStream_t stream) {
  const float* vals = (const float*)d_in[2];
  const float* xd = (const float*)d_in[3];
  const float* yd = (const float*)d_in[4];
  float* out = (float*)d_out;

  if (ws_size >= 40501248ull) {
    char* wsb = (char*)d_ws;
    short* valsT = (short*)wsb;                       // 33554432 B
    short* xbuf  = (short*)(wsb + 33554432);          //  4194304 B
    short* ybuf  = (short*)(wsb + 37748736);          //  2097152 B
    float* ps    = (float*)(wsb + 39845888);          //   524288 B
    float* wv    = (float*)(wsb + 40370176);          //   131072 B

    k_prep1<<<dim3(2560), 256, 0, stream>>>(xd, xbuf, yd, ybuf, ps);
    k_comb<<<dim3(BN * LN / 256), 256, 0, stream>>>(ps, wv);
    k_prep2<<<dim3(4096), 256, 0, stream>>>(vals, wv, valsT);
    k_main8<<<dim3(512), 256, 0, stream>>>(valsT, xbuf, ybuf, out);
  } else {
    float* mz = (float*)d_ws;
    k_stats_o<<<dim3(LN / 64, BN), 256, 0, stream>>>(xd, yd, mz);
    k_main_o<<<dim3(HN / 128, EN / 256, BN), 512, 0, stream>>>(vals, xd, yd, mz, out);
  }
}

// Round 10
// 203.568 us; speedup vs baseline: 1.1023x; 1.1023x over previous
//
#include <hip/hip_runtime.h>
#include <hip/hip_bf16.h>

#define BN 8
#define LN 4096
#define HN 2048
#define EN 512
#define KN 64
#define NIT 128

typedef __attribute__((ext_vector_type(8))) short bf16x8;
typedef __attribute__((ext_vector_type(4))) float f32x4;
typedef __attribute__((ext_vector_type(16))) float f32x16;
typedef __attribute__((ext_vector_type(4))) unsigned u32x4;

__device__ __forceinline__ short f2b(float x) {
  union { float f; unsigned u; } v; v.f = x;
  unsigned r = v.u + 0x7fffu + ((v.u >> 16) & 1u);  // RNE f32->bf16
  return (short)(r >> 16);
}

__device__ __forceinline__ bf16x8 cvt8s(const float* __restrict__ p, float s) {
  f32x4 a = *(const f32x4*)(p);
  f32x4 b = *(const f32x4*)(p + 4);
  bf16x8 r;
  r[0] = f2b(a[0] * s); r[1] = f2b(a[1] * s); r[2] = f2b(a[2] * s); r[3] = f2b(a[3] * s);
  r[4] = f2b(b[0] * s); r[5] = f2b(b[1] * s); r[6] = f2b(b[2] * s); r[7] = f2b(b[3] * s);
  return r;
}

__device__ __forceinline__ void gload16(const void* g, void* s) {
  __builtin_amdgcn_global_load_lds(
      (const __attribute__((address_space(1))) unsigned int*)(unsigned long long)g,
      (__attribute__((address_space(3))) unsigned int*)(unsigned int)(unsigned long long)s,
      16, 0, 0);
}

// ---------- stats: ps[hc][b][l] = sum over 512 h of 2^u (raw f32 in, f2b rounding) ----------
__global__ __launch_bounds__(256) void k_stats(const float* __restrict__ xd,
                                               const float* __restrict__ yd,
                                               float* __restrict__ ps) {
  const int idx = blockIdx.x;
  const int tid = threadIdx.x;
  const float c0 = 0.125f * 1.4426950408889634f;
  const int b = (idx >> 5) & 7, hc = idx >> 8;
  const int w = tid >> 6, lane = tid & 63;
  const int row = lane & 15, g = lane >> 4;
  const int lb = (idx & 31) * 128 + w * 32;
  const size_t bL = (size_t)b * LN, bH = (size_t)b * HN;
  bf16x8 xa[2][2];
#pragma unroll
  for (int lt = 0; lt < 2; ++lt) {
    const float* xp = xd + (bL + lb + lt * 16 + row) * KN + g * 8;
    xa[lt][0] = cvt8s(xp, c0);
    xa[lt][1] = cvt8s(xp + 32, c0);
  }
  float s[2][4] = {{0.f, 0.f, 0.f, 0.f}, {0.f, 0.f, 0.f, 0.f}};
  const float* ybase = yd + (bH + hc * 512 + row) * KN + g * 8;
#pragma unroll 2
  for (int it = 0; it < 32; ++it) {
    const float* yp = ybase + (size_t)it * (16 * KN);
    bf16x8 y0 = cvt8s(yp, 1.0f);
    bf16x8 y1 = cvt8s(yp + 32, 1.0f);
#pragma unroll
    for (int lt = 0; lt < 2; ++lt) {
      f32x4 a = {0.f, 0.f, 0.f, 0.f};
      a = __builtin_amdgcn_mfma_f32_16x16x32_bf16(xa[lt][0], y0, a, 0, 0, 0);
      a = __builtin_amdgcn_mfma_f32_16x16x32_bf16(xa[lt][1], y1, a, 0, 0, 0);
#pragma unroll
      for (int r = 0; r < 4; ++r) s[lt][r] += __builtin_amdgcn_exp2f(a[r]);
    }
  }
#pragma unroll
  for (int d = 1; d < 16; d <<= 1)
#pragma unroll
    for (int lt = 0; lt < 2; ++lt)
#pragma unroll
      for (int r = 0; r < 4; ++r) s[lt][r] += __shfl_xor(s[lt][r], d);
  if (row == 0) {
#pragma unroll
    for (int lt = 0; lt < 2; ++lt)
#pragma unroll
      for (int r = 0; r < 4; ++r)
        ps[(size_t)hc * (BN * LN) + bL + lb + lt * 16 + 4 * g + r] = s[lt][r];
  }
}

// ---------- merge: cvt x/y (0..1535) | prep_v with inline 1/Z (1536..5631) ----------
__global__ __launch_bounds__(256) void k_merge(const float* __restrict__ xd,
                                               short* __restrict__ xo,
                                               const float* __restrict__ yd,
                                               short* __restrict__ yo,
                                               const float* __restrict__ vals,
                                               const float* __restrict__ ps,
                                               short* __restrict__ valsT) {
  __shared__ unsigned trT[2048];
  const int bx = blockIdx.x;
  const int tid = threadIdx.x;
  const float c0 = 0.125f * 1.4426950408889634f;
  if (bx < 1536) {
    const float* src;
    short* dst;
    float scale;
    int i;
    if (bx < 1024) { i = bx * 256 + tid; src = xd; dst = xo; scale = c0; }
    else           { i = (bx - 1024) * 256 + tid; src = yd; dst = yo; scale = 1.0f; }
    *(bf16x8*)(dst + (size_t)i * 8) = cvt8s(src + (size_t)i * 8, scale);
  } else {
    const int idx = bx - 1536;
    const int b = idx >> 9;
    const int e0 = ((idx >> 6) & 7) * 64;
    const int l0 = (idx & 63) * 64;
    {
      int lr2 = tid >> 3;
      int ec = (tid & 7) * 8;
      size_t li0 = (size_t)b * LN + l0 + 2 * lr2;
      const float* r0 = vals + li0 * EN + e0 + ec;
      const float* r1 = r0 + EN;
      float w0 = 1.0f / (ps[li0] + ps[BN * LN + li0] + ps[2 * BN * LN + li0] + ps[3 * BN * LN + li0]);
      float w1 = 1.0f / (ps[li0 + 1] + ps[BN * LN + li0 + 1] + ps[2 * BN * LN + li0 + 1] + ps[3 * BN * LN + li0 + 1]);
      f32x4 a0 = *(const f32x4*)r0, a1 = *(const f32x4*)(r0 + 4);
      f32x4 cc0 = *(const f32x4*)r1, cc1 = *(const f32x4*)(r1 + 4);
#pragma unroll
      for (int j = 0; j < 8; ++j) {
        float lo = ((j < 4) ? a0[j] : a1[j - 4]) * w0;
        float hi = ((j < 4) ? cc0[j] : cc1[j - 4]) * w1;
        unsigned dw = (unsigned)(unsigned short)f2b(lo) |
                      ((unsigned)(unsigned short)f2b(hi) << 16);
        int e = ec + j;
        int sz = (((e >> 3) ^ e) & 7) << 2;
        trT[e * 32 + (lr2 ^ sz)] = dw;
      }
    }
    __syncthreads();
    {
      int er = tid >> 2, lq = (tid & 3) * 8;
      int sr = ((er >> 3) ^ er) & 7;
      const unsigned* base = trT + er * 32;
      u32x4 u0 = *(const u32x4*)(base + ((((lq >> 2) + 0) ^ sr) << 2));
      u32x4 u1 = *(const u32x4*)(base + ((((lq >> 2) + 1) ^ sr) << 2));
      short* dst = valsT + ((size_t)b * EN + e0 + er) * LN + l0 + 2 * lq;
      *(u32x4*)dst = u0;
      *(u32x4*)(dst + 8) = u1;
    }
  }
}

// ---------- main v9: v8 with FIXED vT swizzle ((e>>1)&3) ----------
// 4 waves, wave tile 32h x 128e, LT=32, 1 barrier/iter, in-register P.
// LDS: vT[3]x16384 @0 | xT[3]x4096 @49152
__global__ __launch_bounds__(256, 2) void k_main9(
    const short* __restrict__ valsT, const short* __restrict__ xb,
    const short* __restrict__ yb, float* __restrict__ out) {
  __shared__ __align__(16) char smem[61440];
  const int tid = threadIdx.x;
  const int w = tid >> 6, lane = tid & 63;
  const int l5 = lane & 31, hi = lane >> 5;

  const int f = blockIdx.x;
  const int b = f & 7;                 // XCD f%8 <- batch b (valsT[b] 4MB per XCD L2)
  const int rest = f >> 3;             // 0..63
  const int hb = (rest & 31) * 64;
  const int eb = (rest >> 5) * 256;
  const size_t bL = (size_t)b * LN, bH = (size_t)b * HN;
  const int hh = w >> 1, eq = w & 1;

  // ---- staging source pointers (pre-swizzled global, linear LDS dest) ----
  const short* vsrc[4];
#pragma unroll
  for (int j = 0; j < 4; ++j) {
    int i = j * 256 + tid;
    int e = i >> 2, c = i & 3, sl = c ^ ((e >> 1) & 3);   // FIXED swizzle
    vsrc[j] = valsT + (((size_t)b * EN + eb + e) << 12) + 8 * sl;
  }
  const short* xsrc = xb + ((bL + (tid >> 3)) << 6) + 8 * ((tid & 7) ^ ((tid >> 3) & 7));

  auto stage = [&](int t) {
    int m3 = t % 3;
    gload16(xsrc + ((size_t)t << 11), smem + 49152 + m3 * 4096 + tid * 16);
#pragma unroll
    for (int j = 0; j < 4; ++j)
      gload16(vsrc[j] + t * 32, smem + m3 * 16384 + (j * 256 + tid) * 16);
  };

  // ---- y B-frags (loop-invariant) ----
  bf16x8 ya[4];
  {
    const short* yp = yb + ((bH + hb + hh * 32 + l5) << 6) + hi * 8;
#pragma unroll
    for (int kf = 0; kf < 4; ++kf) ya[kf] = *(const bf16x8*)(yp + kf * 16);
  }
  // xT read offsets: row l5 (128B), chunk (2kf+hi)^(l5&7)
  int xoff[4];
#pragma unroll
  for (int kf = 0; kf < 4; ++kf)
    xoff[kf] = l5 * 128 + (((2 * kf + hi) ^ (l5 & 7)) << 4);
  // vT read offsets: row e (64B), chunk (2kh+hi)^((e>>1)&3)  -- FIXED
  int voff[4][2];
#pragma unroll
  for (int et = 0; et < 4; ++et) {
    int e = eq * 128 + et * 32 + l5;
#pragma unroll
    for (int kh = 0; kh < 2; ++kh)
      voff[et][kh] = e * 64 + (((2 * kh + hi) ^ ((e >> 1) & 3)) << 4);
  }

  f32x16 acc[4];
#pragma unroll
  for (int et = 0; et < 4; ++et)
#pragma unroll
    for (int q = 0; q < 16; ++q) acc[et][q] = 0.f;

  // ---- prologue: stage 0,1; drain tile0's 5, leave tile1's 5 in flight ----
  stage(0);
  stage(1);
  asm volatile("s_waitcnt vmcnt(5)" ::: "memory");
  __builtin_amdgcn_s_barrier();
  asm volatile("" ::: "memory");

  for (int it = 0; it < NIT; ++it) {
    const char* vbuf = smem + (it % 3) * 16384;
    const char* xbuf = smem + 49152 + (it % 3) * 4096;
    if (it + 2 < NIT) stage(it + 2);

    bf16x8 vb[4][2];
#pragma unroll
    for (int et = 0; et < 4; ++et) {
      vb[et][0] = *(const bf16x8*)(vbuf + voff[et][0]);
      vb[et][1] = *(const bf16x8*)(vbuf + voff[et][1]);
    }

    // produce S^T: D[row=l][col=h] (32x32, K=64)
    f32x16 d;
#pragma unroll
    for (int q = 0; q < 16; ++q) d[q] = 0.f;
#pragma unroll
    for (int kf = 0; kf < 4; ++kf) {
      bf16x8 xa = *(const bf16x8*)(xbuf + xoff[kf]);
      d = __builtin_amdgcn_mfma_f32_32x32x16_bf16(xa, ya[kf], d, 0, 0, 0);
    }

    // P = exp2(S) -> bf16 pairs -> permlane32_swap into A-frag layout
    int dw[8];
#pragma unroll
    for (int q = 0; q < 8; ++q) {
      float plo = __builtin_amdgcn_exp2f(d[2 * q]);
      float phi = __builtin_amdgcn_exp2f(d[2 * q + 1]);
      asm("v_cvt_pk_bf16_f32 %0, %1, %2" : "=v"(dw[q]) : "v"(plo), "v"(phi));
    }
    asm volatile("v_permlane32_swap_b32 %0, %1" : "+v"(dw[0]), "+v"(dw[2]));
    asm volatile("v_permlane32_swap_b32 %0, %1" : "+v"(dw[1]), "+v"(dw[3]));
    asm volatile("v_permlane32_swap_b32 %0, %1" : "+v"(dw[4]), "+v"(dw[6]));
    asm volatile("v_permlane32_swap_b32 %0, %1" : "+v"(dw[5]), "+v"(dw[7]));
    union { int i[4]; bf16x8 v; } pa0, pa1;
    pa0.i[0] = dw[0]; pa0.i[1] = dw[1]; pa0.i[2] = dw[2]; pa0.i[3] = dw[3];
    pa1.i[0] = dw[4]; pa1.i[1] = dw[5]; pa1.i[2] = dw[6]; pa1.i[3] = dw[7];

    // consume: acc[h][e] += P x V'
    __builtin_amdgcn_s_setprio(1);
#pragma unroll
    for (int et = 0; et < 4; ++et) {
      acc[et] = __builtin_amdgcn_mfma_f32_32x32x16_bf16(pa0.v, vb[et][0], acc[et], 0, 0, 0);
      acc[et] = __builtin_amdgcn_mfma_f32_32x32x16_bf16(pa1.v, vb[et][1], acc[et], 0, 0, 0);
    }
    __builtin_amdgcn_s_setprio(0);

    if (it < NIT - 1) {
      if (it < NIT - 2)
        asm volatile("s_waitcnt vmcnt(5) lgkmcnt(0)" ::: "memory");
      else
        asm volatile("s_waitcnt vmcnt(0) lgkmcnt(0)" ::: "memory");
      __builtin_amdgcn_s_barrier();
      asm volatile("" ::: "memory");
    }
  }

  // ---- epilogue: D col=lane&31 (e), row=(r&3)+8*(r>>2)+4*hi (h) ----
#pragma unroll
  for (int et = 0; et < 4; ++et)
#pragma unroll
    for (int r = 0; r < 16; ++r) {
      int h = hb + hh * 32 + (r & 3) + 8 * (r >> 2) + 4 * hi;
      int e = eb + eq * 128 + et * 32 + l5;
      out[(bH + h) * (size_t)EN + e] = acc[et][r];
    }
}

// ================= fallback path (round-1 kernels, ws < 40.5 MB) =================
__global__ __launch_bounds__(256) void k_stats_o(const float* __restrict__ xd,
                                                 const float* __restrict__ yd,
                                                 float* __restrict__ mz) {
  const int b = blockIdx.y;
  const int w = threadIdx.x >> 6;
  const int lane = threadIdx.x & 63;
  const int row = lane & 15, g = lane >> 4;
  const int lb = blockIdx.x * 64 + w * 16;
  const float* xp = xd + ((size_t)b * LN + lb + row) * KN + g * 8;
  bf16x8 a0 = cvt8s(xp, 1.0f), a1 = cvt8s(xp + 32, 1.0f);
  float m[4], s[4];
#pragma unroll
  for (int r = 0; r < 4; ++r) { m[r] = -1e30f; s[r] = 0.f; }
  const float* ybp = yd + ((size_t)b * HN + row) * KN + g * 8;
  for (int h0 = 0; h0 < HN; h0 += 16) {
    bf16x8 b0 = cvt8s(ybp + (size_t)h0 * KN, 1.0f);
    bf16x8 b1 = cvt8s(ybp + (size_t)h0 * KN + 32, 1.0f);
    f32x4 acc = {0.f, 0.f, 0.f, 0.f};
    acc = __builtin_amdgcn_mfma_f32_16x16x32_bf16(a0, b0, acc, 0, 0, 0);
    acc = __builtin_amdgcn_mfma_f32_16x16x32_bf16(a1, b1, acc, 0, 0, 0);
#pragma unroll
    for (int r = 0; r < 4; ++r) {
      float v = acc[r] * 0.125f;
      float mn = fmaxf(m[r], v);
      s[r] = s[r] * __expf(m[r] - mn) + __expf(v - mn);
      m[r] = mn;
    }
  }
#pragma unroll
  for (int d = 1; d < 16; d <<= 1) {
#pragma unroll
    for (int r = 0; r < 4; ++r) {
      float mo = __shfl_xor(m[r], d);
      float so = __shfl_xor(s[r], d);
      float mn = fmaxf(m[r], mo);
      s[r] = s[r] * __expf(m[r] - mn) + so * __expf(mo - mn);
      m[r] = mn;
    }
  }
  if (row == 0) {
#pragma unroll
    for (int r = 0; r < 4; ++r) {
      size_t idx = (size_t)b * LN + lb + 4 * g + r;
      mz[idx] = m[r];
      mz[(size_t)BN * LN + idx] = 1.0f / s[r];
    }
  }
}

__global__ __launch_bounds__(512) void k_main_o(const float* __restrict__ vals,
                                                const float* __restrict__ xd,
                                                const float* __restrict__ yd,
                                                const float* __restrict__ mz,
                                                float* __restrict__ out) {
  __shared__ short vT[256][34];
  __shared__ short pT[128][34];
  __shared__ short xT[32][72];
  __shared__ float smm[32], smz[32];
  const int b = blockIdx.z;
  const int hb = blockIdx.x * 128;
  const int eb = blockIdx.y * 256;
  const int tid = threadIdx.x;
  const int w = tid >> 6, lane = tid & 63;
  const int row = lane & 15, g = lane >> 4;
  const float* yp = yd + ((size_t)b * HN + hb + w * 16 + row) * KN + g * 8;
  bf16x8 ya0 = cvt8s(yp, 1.0f), ya1 = cvt8s(yp + 32, 1.0f);
  f32x4 acc[16];
#pragma unroll
  for (int n = 0; n < 16; ++n) acc[n] = (f32x4){0.f, 0.f, 0.f, 0.f};
  const float* mzb = mz + (size_t)b * LN;
  const float* rzb = mz + (size_t)BN * LN + (size_t)b * LN;
  for (int l0 = 0; l0 < LN; l0 += 32) {
    __syncthreads();
    {
      int xl = tid >> 4, xk = (tid & 15) * 4;
      f32x4 xv = *(const f32x4*)(xd + ((size_t)b * LN + l0 + xl) * KN + xk);
      union { short h[4]; int i[2]; } u;
      u.h[0] = f2b(xv[0]); u.h[1] = f2b(xv[1]); u.h[2] = f2b(xv[2]); u.h[3] = f2b(xv[3]);
      int* dst = (int*)(&xT[xl][xk]);
      dst[0] = u.i[0]; dst[1] = u.i[1];
    }
#pragma unroll
    for (int lp = 0; lp < 4; ++lp) {
      int vl = (tid >> 6) + lp * 8;
      const float* vrow = vals + ((size_t)b * LN + l0 + vl) * EN + eb;
#pragma unroll
      for (int u2 = 0; u2 < 4; ++u2) {
        int e = (tid & 63) + u2 * 64;
        vT[e][vl] = f2b(vrow[e]);
      }
    }
    if (tid < 32) { smm[tid] = mzb[l0 + tid]; smz[tid] = rzb[l0 + tid]; }
    __syncthreads();
#pragma unroll
    for (int t2 = 0; t2 < 2; ++t2) {
      const short* xr = &xT[t2 * 16 + row][0];
      bf16x8 xb0 = *(const bf16x8*)(xr + 8 * g);
      bf16x8 xb1 = *(const bf16x8*)(xr + 32 + 8 * g);
      f32x4 sa = {0.f, 0.f, 0.f, 0.f};
      sa = __builtin_amdgcn_mfma_f32_16x16x32_bf16(ya0, xb0, sa, 0, 0, 0);
      sa = __builtin_amdgcn_mfma_f32_16x16x32_bf16(ya1, xb1, sa, 0, 0, 0);
      int lcol = t2 * 16 + row;
      float mm = smm[lcol], zz = smz[lcol];
#pragma unroll
      for (int r = 0; r < 4; ++r) {
        float p2 = __expf(sa[r] * 0.125f - mm) * zz;
        pT[w * 16 + 4 * g + r][lcol] = f2b(p2);
      }
    }
    __syncthreads();
    bf16x8 pa;
    {
      const int* pi = (const int*)(&pT[w * 16 + row][0] + 8 * g);
      union { int i[4]; bf16x8 f; } u;
      u.i[0] = pi[0]; u.i[1] = pi[1]; u.i[2] = pi[2]; u.i[3] = pi[3];
      pa = u.f;
    }
#pragma unroll
    for (int n = 0; n < 16; ++n) {
      const int* vi = (const int*)(&vT[n * 16 + row][0] + 8 * g);
      union { int i[4]; bf16x8 f; } u;
      u.i[0] = vi[0]; u.i[1] = vi[1]; u.i[2] = vi[2]; u.i[3] = vi[3];
      acc[n] = __builtin_amdgcn_mfma_f32_16x16x32_bf16(pa, u.f, acc[n], 0, 0, 0);
    }
  }
#pragma unroll
  for (int n = 0; n < 16; ++n)
#pragma unroll
    for (int r = 0; r < 4; ++r) {
      int h = hb + w * 16 + 4 * g + r;
      int e = eb + n * 16 + row;
      out[((size_t)b * HN + h) * EN + e] = acc[n][r];
    }
}

extern "C" void kernel_launch(void* const* d_in, const int* in_sizes, int n_in,
                              void* d_out, int out_size, void* d_ws, size_t ws_size,
                              hipStream_t stream) {
  const float* vals = (const float*)d_in[2];
  const float* xd = (const float*)d_in[3];
  const float* yd = (const float*)d_in[4];
  float* out = (float*)d_out;

  if (ws_size >= 40501248ull) {
    char* wsb = (char*)d_ws;
    short* valsT = (short*)wsb;                       // 33554432 B
    short* xbuf  = (short*)(wsb + 33554432);          //  4194304 B
    short* ybuf  = (short*)(wsb + 37748736);          //  2097152 B
    float* ps    = (float*)(wsb + 39845888);          //   524288 B

    k_stats<<<dim3(1024), 256, 0, stream>>>(xd, yd, ps);
    k_merge<<<dim3(5632), 256, 0, stream>>>(xd, xbuf, yd, ybuf, vals, ps, valsT);
    k_main9<<<dim3(512), 256, 0, stream>>>(valsT, xbuf, ybuf, out);
  } else {
    float* mz = (float*)d_ws;
    k_stats_o<<<dim3(LN / 64, BN), 256, 0, stream>>>(xd, yd, mz);
    k_main_o<<<dim3(HN / 128, EN / 256, BN), 512, 0, stream>>>(vals, xd, yd, mz, out);
  }
}

// Round 13
// 201.487 us; speedup vs baseline: 1.1137x; 1.0103x over previous
//
#include <hip/hip_runtime.h>
#include <hip/hip_bf16.h>

#define BN 8
#define LN 4096
#define HN 2048
#define EN 512
#define KN 64
#define NIT 128

typedef __attribute__((ext_vector_type(8))) short bf16x8;
typedef __attribute__((ext_vector_type(4))) float f32x4;
typedef __attribute__((ext_vector_type(16))) float f32x16;
typedef __attribute__((ext_vector_type(4))) unsigned u32x4;

__device__ __forceinline__ short f2b(float x) {
  union { float f; unsigned u; } v; v.f = x;
  unsigned r = v.u + 0x7fffu + ((v.u >> 16) & 1u);  // RNE f32->bf16
  return (short)(r >> 16);
}

__device__ __forceinline__ bf16x8 cvt8s(const float* __restrict__ p, float s) {
  f32x4 a = *(const f32x4*)(p);
  f32x4 b = *(const f32x4*)(p + 4);
  bf16x8 r;
  r[0] = f2b(a[0] * s); r[1] = f2b(a[1] * s); r[2] = f2b(a[2] * s); r[3] = f2b(a[3] * s);
  r[4] = f2b(b[0] * s); r[5] = f2b(b[1] * s); r[6] = f2b(b[2] * s); r[7] = f2b(b[3] * s);
  return r;
}

__device__ __forceinline__ void gload16(const void* g, void* s) {
  __builtin_amdgcn_global_load_lds(
      (const __attribute__((address_space(1))) unsigned int*)(unsigned long long)g,
      (__attribute__((address_space(3))) unsigned int*)(unsigned int)(unsigned long long)s,
      16, 0, 0);
}

// ---------- stats: ps[hc][b][l] = sum over 512 h of 2^u (raw f32 in, f2b rounding) ----------
__global__ __launch_bounds__(256) void k_stats(const float* __restrict__ xd,
                                               const float* __restrict__ yd,
                                               float* __restrict__ ps) {
  const int idx = blockIdx.x;
  const int tid = threadIdx.x;
  const float c0 = 0.125f * 1.4426950408889634f;
  const int b = (idx >> 5) & 7, hc = idx >> 8;
  const int w = tid >> 6, lane = tid & 63;
  const int row = lane & 15, g = lane >> 4;
  const int lb = (idx & 31) * 128 + w * 32;
  const size_t bL = (size_t)b * LN, bH = (size_t)b * HN;
  bf16x8 xa[2][2];
#pragma unroll
  for (int lt = 0; lt < 2; ++lt) {
    const float* xp = xd + (bL + lb + lt * 16 + row) * KN + g * 8;
    xa[lt][0] = cvt8s(xp, c0);
    xa[lt][1] = cvt8s(xp + 32, c0);
  }
  float s[2][4] = {{0.f, 0.f, 0.f, 0.f}, {0.f, 0.f, 0.f, 0.f}};
  const float* ybase = yd + (bH + hc * 512 + row) * KN + g * 8;
#pragma unroll 2
  for (int it = 0; it < 32; ++it) {
    const float* yp = ybase + (size_t)it * (16 * KN);
    bf16x8 y0 = cvt8s(yp, 1.0f);
    bf16x8 y1 = cvt8s(yp + 32, 1.0f);
#pragma unroll
    for (int lt = 0; lt < 2; ++lt) {
      f32x4 a = {0.f, 0.f, 0.f, 0.f};
      a = __builtin_amdgcn_mfma_f32_16x16x32_bf16(xa[lt][0], y0, a, 0, 0, 0);
      a = __builtin_amdgcn_mfma_f32_16x16x32_bf16(xa[lt][1], y1, a, 0, 0, 0);
#pragma unroll
      for (int r = 0; r < 4; ++r) s[lt][r] += __builtin_amdgcn_exp2f(a[r]);
    }
  }
#pragma unroll
  for (int d = 1; d < 16; d <<= 1)
#pragma unroll
    for (int lt = 0; lt < 2; ++lt)
#pragma unroll
      for (int r = 0; r < 4; ++r) s[lt][r] += __shfl_xor(s[lt][r], d);
  if (row == 0) {
#pragma unroll
    for (int lt = 0; lt < 2; ++lt)
#pragma unroll
      for (int r = 0; r < 4; ++r)
        ps[(size_t)hc * (BN * LN) + bL + lb + lt * 16 + 4 * g + r] = s[lt][r];
  }
}

// ---------- merge: cvt x/y (0..1535) | prep_v with inline 1/Z (1536..5631) ----------
__global__ __launch_bounds__(256) void k_merge(const float* __restrict__ xd,
                                               short* __restrict__ xo,
                                               const float* __restrict__ yd,
                                               short* __restrict__ yo,
                                               const float* __restrict__ vals,
                                               const float* __restrict__ ps,
                                               short* __restrict__ valsT) {
  __shared__ unsigned trT[2048];
  const int bx = blockIdx.x;
  const int tid = threadIdx.x;
  const float c0 = 0.125f * 1.4426950408889634f;
  if (bx < 1536) {
    const float* src;
    short* dst;
    float scale;
    int i;
    if (bx < 1024) { i = bx * 256 + tid; src = xd; dst = xo; scale = c0; }
    else           { i = (bx - 1024) * 256 + tid; src = yd; dst = yo; scale = 1.0f; }
    *(bf16x8*)(dst + (size_t)i * 8) = cvt8s(src + (size_t)i * 8, scale);
  } else {
    const int idx = bx - 1536;
    const int b = idx >> 9;
    const int e0 = ((idx >> 6) & 7) * 64;
    const int l0 = (idx & 63) * 64;
    {
      int lr2 = tid >> 3;
      int ec = (tid & 7) * 8;
      size_t li0 = (size_t)b * LN + l0 + 2 * lr2;
      const float* r0 = vals + li0 * EN + e0 + ec;
      const float* r1 = r0 + EN;
      float w0 = 1.0f / (ps[li0] + ps[BN * LN + li0] + ps[2 * BN * LN + li0] + ps[3 * BN * LN + li0]);
      float w1 = 1.0f / (ps[li0 + 1] + ps[BN * LN + li0 + 1] + ps[2 * BN * LN + li0 + 1] + ps[3 * BN * LN + li0 + 1]);
      f32x4 a0 = *(const f32x4*)r0, a1 = *(const f32x4*)(r0 + 4);
      f32x4 cc0 = *(const f32x4*)r1, cc1 = *(const f32x4*)(r1 + 4);
#pragma unroll
      for (int j = 0; j < 8; ++j) {
        float lo = ((j < 4) ? a0[j] : a1[j - 4]) * w0;
        float hi = ((j < 4) ? cc0[j] : cc1[j - 4]) * w1;
        unsigned dw = (unsigned)(unsigned short)f2b(lo) |
                      ((unsigned)(unsigned short)f2b(hi) << 16);
        int e = ec + j;
        int sz = (((e >> 3) ^ e) & 7) << 2;
        trT[e * 32 + (lr2 ^ sz)] = dw;
      }
    }
    __syncthreads();
    {
      int er = tid >> 2, lq = (tid & 3) * 8;
      int sr = ((er >> 3) ^ er) & 7;
      const unsigned* base = trT + er * 32;
      u32x4 u0 = *(const u32x4*)(base + ((((lq >> 2) + 0) ^ sr) << 2));
      u32x4 u1 = *(const u32x4*)(base + ((((lq >> 2) + 1) ^ sr) << 2));
      short* dst = valsT + ((size_t)b * EN + e0 + er) * LN + l0 + 2 * lq;
      *(u32x4*)dst = u0;
      *(u32x4*)(dst + 8) = u1;
    }
  }
}

// ---------- main v12: v9 structure (PASSED) + conflict-free swizzles ----------
// 4 waves, wave tile 32h x 128e, 1 barrier/iter, in-register P.
// LDS: vT[3]x16384 @0 | xT[3]x4096 @49152
// Swizzle audit (b128 = 4 phases x 16 lanes; need distinct 16B slots mod 256B/phase):
//   vT: slot=(e&3)*64+phys*16, phys=(2kh+hi)^((e>>2)&3) -> +4 lanes => +1 mod 4 => distinct.
//   xT: slot=(l5&1)*128+phys*16, phys=(2kf+hi)^((l5>>1)&7) -> even/odd groups hit 8 distinct.
__global__ __launch_bounds__(256, 2) void k_main12(
    const short* __restrict__ valsT, const short* __restrict__ xb,
    const short* __restrict__ yb, float* __restrict__ out) {
  __shared__ __align__(16) char smem[61440];
  const int tid = threadIdx.x;
  const int w = tid >> 6, lane = tid & 63;
  const int l5 = lane & 31, hi = lane >> 5;

  const int f = blockIdx.x;
  const int b = f & 7;                 // XCD f%8 <- batch b (valsT[b] 4MB per XCD L2)
  const int rest = f >> 3;             // 0..63
  const int hb = (rest & 31) * 64;
  const int eb = (rest >> 5) * 256;
  const size_t bL = (size_t)b * LN, bH = (size_t)b * HN;
  const int hh = w >> 1, eq = w & 1;

  // ---- staging source pointers (pre-swizzled global, linear LDS dest) ----
  const short* vsrc[4];
#pragma unroll
  for (int j = 0; j < 4; ++j) {
    int i = j * 256 + tid;
    int e = i >> 2, c = i & 3, sl = c ^ ((e >> 2) & 3);   // conflict-free swizzle
    vsrc[j] = valsT + (((size_t)b * EN + eb + e) << 12) + 8 * sl;
  }
  const short* xsrc = xb + ((bL + (tid >> 3)) << 6) + 8 * ((tid & 7) ^ ((tid >> 4) & 7));

  auto stage = [&](int t) {
    int m3 = t % 3;
    gload16(xsrc + ((size_t)t << 11), smem + 49152 + m3 * 4096 + tid * 16);
#pragma unroll
    for (int j = 0; j < 4; ++j)
      gload16(vsrc[j] + t * 32, smem + m3 * 16384 + (j * 256 + tid) * 16);
  };

  // ---- y B-frags (loop-invariant) ----
  bf16x8 ya[4];
  {
    const short* yp = yb + ((bH + hb + hh * 32 + l5) << 6) + hi * 8;
#pragma unroll
    for (int kf = 0; kf < 4; ++kf) ya[kf] = *(const bf16x8*)(yp + kf * 16);
  }
  // xT read: row l5 (128B), chunk (2kf+hi)^((l5>>1)&7)
  int xoff[4];
#pragma unroll
  for (int kf = 0; kf < 4; ++kf)
    xoff[kf] = l5 * 128 + (((2 * kf + hi) ^ ((l5 >> 1) & 7)) << 4);
  // vT read: row e (64B), chunk (2kh+hi)^((e>>2)&3)
  int voff[4][2];
#pragma unroll
  for (int et = 0; et < 4; ++et) {
    int e = eq * 128 + et * 32 + l5;
#pragma unroll
    for (int kh = 0; kh < 2; ++kh)
      voff[et][kh] = e * 64 + (((2 * kh + hi) ^ ((e >> 2) & 3)) << 4);
  }

  f32x16 acc[4];
#pragma unroll
  for (int et = 0; et < 4; ++et)
#pragma unroll
    for (int q = 0; q < 16; ++q) acc[et][q] = 0.f;

  // ---- prologue: stage 0,1; drain tile0's 5, leave tile1's 5 in flight ----
  stage(0);
  stage(1);
  asm volatile("s_waitcnt vmcnt(5)" ::: "memory");
  __builtin_amdgcn_s_barrier();
  asm volatile("" ::: "memory");

  for (int it = 0; it < NIT; ++it) {
    const char* vbuf = smem + (it % 3) * 16384;
    const char* xbuf = smem + 49152 + (it % 3) * 4096;
    if (it + 2 < NIT) stage(it + 2);

    bf16x8 vb[4][2];
#pragma unroll
    for (int et = 0; et < 4; ++et) {
      vb[et][0] = *(const bf16x8*)(vbuf + voff[et][0]);
      vb[et][1] = *(const bf16x8*)(vbuf + voff[et][1]);
    }

    // produce S^T: D[row=l][col=h] (32x32, K=64)
    f32x16 d;
#pragma unroll
    for (int q = 0; q < 16; ++q) d[q] = 0.f;
#pragma unroll
    for (int kf = 0; kf < 4; ++kf) {
      bf16x8 xa = *(const bf16x8*)(xbuf + xoff[kf]);
      d = __builtin_amdgcn_mfma_f32_32x32x16_bf16(xa, ya[kf], d, 0, 0, 0);
    }

    // P = exp2(S) -> bf16 pairs -> permlane32_swap into A-frag layout
    int dw[8];
#pragma unroll
    for (int q = 0; q < 8; ++q) {
      float plo = __builtin_amdgcn_exp2f(d[2 * q]);
      float phi = __builtin_amdgcn_exp2f(d[2 * q + 1]);
      asm("v_cvt_pk_bf16_f32 %0, %1, %2" : "=v"(dw[q]) : "v"(plo), "v"(phi));
    }
    asm volatile("v_permlane32_swap_b32 %0, %1" : "+v"(dw[0]), "+v"(dw[2]));
    asm volatile("v_permlane32_swap_b32 %0, %1" : "+v"(dw[1]), "+v"(dw[3]));
    asm volatile("v_permlane32_swap_b32 %0, %1" : "+v"(dw[4]), "+v"(dw[6]));
    asm volatile("v_permlane32_swap_b32 %0, %1" : "+v"(dw[5]), "+v"(dw[7]));
    union { int i[4]; bf16x8 v; } pa0, pa1;
    pa0.i[0] = dw[0]; pa0.i[1] = dw[1]; pa0.i[2] = dw[2]; pa0.i[3] = dw[3];
    pa1.i[0] = dw[4]; pa1.i[1] = dw[5]; pa1.i[2] = dw[6]; pa1.i[3] = dw[7];

    // consume: acc[h][e] += P x V'
    __builtin_amdgcn_s_setprio(1);
#pragma unroll
    for (int et = 0; et < 4; ++et) {
      acc[et] = __builtin_amdgcn_mfma_f32_32x32x16_bf16(pa0.v, vb[et][0], acc[et], 0, 0, 0);
      acc[et] = __builtin_amdgcn_mfma_f32_32x32x16_bf16(pa1.v, vb[et][1], acc[et], 0, 0, 0);
    }
    __builtin_amdgcn_s_setprio(0);

    if (it < NIT - 1) {
      if (it < NIT - 2)
        asm volatile("s_waitcnt vmcnt(5) lgkmcnt(0)" ::: "memory");
      else
        asm volatile("s_waitcnt vmcnt(0) lgkmcnt(0)" ::: "memory");
      __builtin_amdgcn_s_barrier();
      asm volatile("" ::: "memory");
    }
  }

  // ---- epilogue: D col=lane&31 (e), row=(r&3)+8*(r>>2)+4*hi (h) ----
#pragma unroll
  for (int et = 0; et < 4; ++et)
#pragma unroll
    for (int r = 0; r < 16; ++r) {
      int h = hb + hh * 32 + (r & 3) + 8 * (r >> 2) + 4 * hi;
      int e = eb + eq * 128 + et * 32 + l5;
      out[(bH + h) * (size_t)EN + e] = acc[et][r];
    }
}

// ================= fallback path (round-1 kernels, ws < 40.5 MB) =================
__global__ __launch_bounds__(256) void k_stats_o(const float* __restrict__ xd,
                                                 const float* __restrict__ yd,
                                                 float* __restrict__ mz) {
  const int b = blockIdx.y;
  const int w = threadIdx.x >> 6;
  const int lane = threadIdx.x & 63;
  const int row = lane & 15, g = lane >> 4;
  const int lb = blockIdx.x * 64 + w * 16;
  const float* xp = xd + ((size_t)b * LN + lb + row) * KN + g * 8;
  bf16x8 a0 = cvt8s(xp, 1.0f), a1 = cvt8s(xp + 32, 1.0f);
  float m[4], s[4];
#pragma unroll
  for (int r = 0; r < 4; ++r) { m[r] = -1e30f; s[r] = 0.f; }
  const float* ybp = yd + ((size_t)b * HN + row) * KN + g * 8;
  for (int h0 = 0; h0 < HN; h0 += 16) {
    bf16x8 b0 = cvt8s(ybp + (size_t)h0 * KN, 1.0f);
    bf16x8 b1 = cvt8s(ybp + (size_t)h0 * KN + 32, 1.0f);
    f32x4 acc = {0.f, 0.f, 0.f, 0.f};
    acc = __builtin_amdgcn_mfma_f32_16x16x32_bf16(a0, b0, acc, 0, 0, 0);
    acc = __builtin_amdgcn_mfma_f32_16x16x32_bf16(a1, b1, acc, 0, 0, 0);
#pragma unroll
    for (int r = 0; r < 4; ++r) {
      float v = acc[r] * 0.125f;
      float mn = fmaxf(m[r], v);
      s[r] = s[r] * __expf(m[r] - mn) + __expf(v - mn);
      m[r] = mn;
    }
  }
#pragma unroll
  for (int d = 1; d < 16; d <<= 1) {
#pragma unroll
    for (int r = 0; r < 4; ++r) {
      float mo = __shfl_xor(m[r], d);
      float so = __shfl_xor(s[r], d);
      float mn = fmaxf(m[r], mo);
      s[r] = s[r] * __expf(m[r] - mn) + so * __expf(mo - mn);
      m[r] = mn;
    }
  }
  if (row == 0) {
#pragma unroll
    for (int r = 0; r < 4; ++r) {
      size_t idx = (size_t)b * LN + lb + 4 * g + r;
      mz[idx] = m[r];
      mz[(size_t)BN * LN + idx] = 1.0f / s[r];
    }
  }
}

__global__ __launch_bounds__(512) void k_main_o(const float* __restrict__ vals,
                                                const float* __restrict__ xd,
                                                const float* __restrict__ yd,
                                                const float* __restrict__ mz,
                                                float* __restrict__ out) {
  __shared__ short vT[256][34];
  __shared__ short pT[128][34];
  __shared__ short xT[32][72];
  __shared__ float smm[32], smz[32];
  const int b = blockIdx.z;
  const int hb = blockIdx.x * 128;
  const int eb = blockIdx.y * 256;
  const int tid = threadIdx.x;
  const int w = tid >> 6, lane = tid & 63;
  const int row = lane & 15, g = lane >> 4;
  const float* yp = yd + ((size_t)b * HN + hb + w * 16 + row) * KN + g * 8;
  bf16x8 ya0 = cvt8s(yp, 1.0f), ya1 = cvt8s(yp + 32, 1.0f);
  f32x4 acc[16];
#pragma unroll
  for (int n = 0; n < 16; ++n) acc[n] = (f32x4){0.f, 0.f, 0.f, 0.f};
  const float* mzb = mz + (size_t)b * LN;
  const float* rzb = mz + (size_t)BN * LN + (size_t)b * LN;
  for (int l0 = 0; l0 < LN; l0 += 32) {
    __syncthreads();
    {
      int xl = tid >> 4, xk = (tid & 15) * 4;
      f32x4 xv = *(const f32x4*)(xd + ((size_t)b * LN + l0 + xl) * KN + xk);
      union { short h[4]; int i[2]; } u;
      u.h[0] = f2b(xv[0]); u.h[1] = f2b(xv[1]); u.h[2] = f2b(xv[2]); u.h[3] = f2b(xv[3]);
      int* dst = (int*)(&xT[xl][xk]);
      dst[0] = u.i[0]; dst[1] = u.i[1];
    }
#pragma unroll
    for (int lp = 0; lp < 4; ++lp) {
      int vl = (tid >> 6) + lp * 8;
      const float* vrow = vals + ((size_t)b * LN + l0 + vl) * EN + eb;
#pragma unroll
      for (int u2 = 0; u2 < 4; ++u2) {
        int e = (tid & 63) + u2 * 64;
        vT[e][vl] = f2b(vrow[e]);
      }
    }
    if (tid < 32) { smm[tid] = mzb[l0 + tid]; smz[tid] = rzb[l0 + tid]; }
    __syncthreads();
#pragma unroll
    for (int t2 = 0; t2 < 2; ++t2) {
      const short* xr = &xT[t2 * 16 + row][0];
      bf16x8 xb0 = *(const bf16x8*)(xr + 8 * g);
      bf16x8 xb1 = *(const bf16x8*)(xr + 32 + 8 * g);
      f32x4 sa = {0.f, 0.f, 0.f, 0.f};
      sa = __builtin_amdgcn_mfma_f32_16x16x32_bf16(ya0, xb0, sa, 0, 0, 0);
      sa = __builtin_amdgcn_mfma_f32_16x16x32_bf16(ya1, xb1, sa, 0, 0, 0);
      int lcol = t2 * 16 + row;
      float mm = smm[lcol], zz = smz[lcol];
#pragma unroll
      for (int r = 0; r < 4; ++r) {
        float p2 = __expf(sa[r] * 0.125f - mm) * zz;
        pT[w * 16 + 4 * g + r][lcol] = f2b(p2);
      }
    }
    __syncthreads();
    bf16x8 pa;
    {
      const int* pi = (const int*)(&pT[w * 16 + row][0] + 8 * g);
      union { int i[4]; bf16x8 f; } u;
      u.i[0] = pi[0]; u.i[1] = pi[1]; u.i[2] = pi[2]; u.i[3] = pi[3];
      pa = u.f;
    }
#pragma unroll
    for (int n = 0; n < 16; ++n) {
      const int* vi = (const int*)(&vT[n * 16 + row][0] + 8 * g);
      union { int i[4]; bf16x8 f; } u;
      u.i[0] = vi[0]; u.i[1] = vi[1]; u.i[2] = vi[2]; u.i[3] = vi[3];
      acc[n] = __builtin_amdgcn_mfma_f32_16x16x32_bf16(pa, u.f, acc[n], 0, 0, 0);
    }
  }
#pragma unroll
  for (int n = 0; n < 16; ++n)
#pragma unroll
    for (int r = 0; r < 4; ++r) {
      int h = hb + w * 16 + 4 * g + r;
      int e = eb + n * 16 + row;
      out[((size_t)b * HN + h) * EN + e] = acc[n][r];
    }
}

extern "C" void kernel_launch(void* const* d_in, const int* in_sizes, int n_in,
                              void* d_out, int out_size, void* d_ws, size_t ws_size,
                              hipStream_t stream) {
  const float* vals = (const float*)d_in[2];
  const float* xd = (const float*)d_in[3];
  const float* yd = (const float*)d_in[4];
  float* out = (float*)d_out;

  if (ws_size >= 40501248ull) {
    char* wsb = (char*)d_ws;
    short* valsT = (short*)wsb;                       // 33554432 B
    short* xbuf  = (short*)(wsb + 33554432);          //  4194304 B
    short* ybuf  = (short*)(wsb + 37748736);          //  2097152 B
    float* ps    = (float*)(wsb + 39845888);          //   524288 B

    k_stats<<<dim3(1024), 256, 0, stream>>>(xd, yd, ps);
    k_merge<<<dim3(5632), 256, 0, stream>>>(xd, xbuf, yd, ybuf, vals, ps, valsT);
    k_main12<<<dim3(512), 256, 0, stream>>>(valsT, xbuf, ybuf, out);
  } else {
    float* mz = (float*)d_ws;
    k_stats_o<<<dim3(LN / 64, BN), 256, 0, stream>>>(xd, yd, mz);
    k_main_o<<<dim3(HN / 128, EN / 256, BN), 512, 0, stream>>>(vals, xd, yd, mz, out);
  }
}